// Round 7
// baseline (1245.817 us; speedup 1.0000x reference)
//
#include <hip/hip_runtime.h>
#include <hip/hip_bf16.h>

// LIF fused kernel, Round 10: pre-expanded i8 spike array (no in-loop expand).
//
// R9 post-mortem: VALU-issue-bound (VALUBusy 62.4% = 740 cy/t of 1186 wall;
// MfmaUtil 17.4% = i8 MFMA floor ~245 cy/t reached). Largest removable VALU
// block = bits->i8 expand (~20 wave-inst/wave/t), re-done redundantly by all
// 32 g-blocks for the same bytes.
//
// R10: prepass writes spikes directly as i8 bytes {0,1} [T,B,F] (128 MiB,
// HBM-bound ~107us). Main kernel's A-frag = one dwordx4 (16 B) load per
// lane, prefetched 2t deep; byte values identical to R9's expand output ->
// arithmetic bit-identical to R9 (absmax should reproduce 0.0078125).
// W 3-digit quant / 3x mfma_i32_16x16x64_i8 / combine / xbuf / deferred
// LIF / ping-pong / 1 barrier/t: byte-identical to verified R9.
//
// Fallback chain: ws>=128MiB i8 path; ws>=16MiB R9 bits path; else R3 f32.

typedef __attribute__((ext_vector_type(8))) short short8;   // 8 x bf16
typedef __attribute__((ext_vector_type(4))) float floatx4;
typedef __attribute__((ext_vector_type(2))) unsigned uintx2;
typedef __attribute__((ext_vector_type(4))) unsigned uintx4;
typedef __attribute__((ext_vector_type(4))) int int4v;

#define T_STEPS 1024
#define B_DIM   256
#define F_DIM   512
#define BF      (B_DIM * F_DIM)
#define ROWP    520   // (fallback kernel only)

static __device__ __forceinline__ unsigned short f2bf_rne(float f) {
    unsigned u = __float_as_uint(f);
    return (unsigned short)((u + 0x7FFFu + ((u >> 16) & 1u)) >> 16);
}
static __device__ __forceinline__ float bf2f(unsigned short h) {
    return __uint_as_float(((unsigned)h) << 16);
}

// ---------------- prepass A: fp32 {0,1} -> i8 bytes ----------------
// spikes are exactly 0.0f or 1.0f: byte = (u >> 23) & 1.
__global__ __launch_bounds__(256)
void pack_i8_kernel(const float* __restrict__ sp, uintx4* __restrict__ bytes)
{
    const size_t n16 = (size_t)T_STEPS * BF / 16;   // 16 elems per thread-iter
    for (size_t i = blockIdx.x * 256 + threadIdx.x; i < n16; i += 2048 * 256) {
        const floatx4* p = (const floatx4*)(sp + i * 16);
        uintx4 o;
        #pragma unroll
        for (int q = 0; q < 4; ++q) {
            floatx4 f = p[q];
            unsigned u0 = __float_as_uint(f[0]), u1 = __float_as_uint(f[1]);
            unsigned u2 = __float_as_uint(f[2]), u3 = __float_as_uint(f[3]);
            o[q] = ((u0 >> 23) & 1u)        | ((u1 >> 15) & 0x100u)
                 | ((u2 >> 7)  & 0x10000u)  | ((u3 << 1)  & 0x1000000u);
        }
        bytes[i] = o;
    }
}

// ---------------- prepass B: fp32 {0,1} -> bitmask (R9 path) ------------
__global__ __launch_bounds__(256)
void pack_kernel(const float* __restrict__ sp, unsigned* __restrict__ bits)
{
    const int lane = threadIdx.x & 63;
    const int wv   = blockIdx.x * 4 + (threadIdx.x >> 6);
    for (int c = wv; c < 65536; c += 2048 * 4) {
        const float* p = sp + (size_t)c * 2048;
        unsigned val = 0;
        #pragma unroll
        for (int r = 0; r < 32; ++r) {
            float x = p[r * 64 + lane];
            unsigned long long m = __ballot(x != 0.0f);
            unsigned sel = (lane & 1) ? (unsigned)(m >> 32) : (unsigned)m;
            if ((lane >> 1) == r) val = sel;
        }
        bits[(size_t)c * 64 + lane] = val;
    }
}

// ======================= shared W-quant helper ==========================
// Per OUTPUT ROW 24-bit quantization into 3 signed i8 digit planes.
// q = d0*2^16 + d1*2^8 + d2 exactly; |d0| <= 123.  C = 8e6 / rowmax.

// -------- main kernel (R10): i8 A-loads, 8 K-eighth waves ---------------
__global__ __launch_bounds__(512, 4)
void lif_kernel_i8(const unsigned char* __restrict__ a8,
                   const float* __restrict__ W,
                   float* __restrict__ out)
{
    __shared__ float xbuf[2][7 * 256];   // dbuf x 7 partial waves x 16x16 tile
    __shared__ float rowmax[8][16];      // setup-only: per-wave row maxima

    const int tid  = threadIdx.x;
    const int lane = tid & 63;
    const int wq   = tid >> 6;          // 0..7: K-eighth, k in [wq*64, wq*64+64)
    const int bt   = blockIdx.x & 15;
    const int gb   = blockIdx.x >> 4;   // 0..31
    const int b0   = bt * 16;
    const int gw   = gb * 16;
    const int mrow = lane & 15;
    const int lq   = lane >> 4;         // 0..3: k-chunk of 16 within the 64

    // ---- W setup (once): rows gw+mrow, k = wq*64 + lq*16 + j, j=0..15
    int4v wi0, wi1, wi2;
    float invC;
    {
        const float* wp = W + (size_t)(gw + mrow) * F_DIM + wq * 64 + lq * 16;
        float wv[16];
        float lm = 0.0f;
        #pragma unroll
        for (int j = 0; j < 16; ++j) {
            wv[j] = wp[j];
            lm = fmaxf(lm, fabsf(wv[j]));
        }
        lm = fmaxf(lm, __shfl_xor(lm, 16, 64));
        lm = fmaxf(lm, __shfl_xor(lm, 32, 64));
        if (lane < 16) rowmax[wq][lane] = lm;
        __syncthreads();
        float S = 1e-30f;
        #pragma unroll
        for (int w8 = 0; w8 < 8; ++w8) S = fmaxf(S, rowmax[w8][mrow]);
        __syncthreads();   // rowmax consumed before later LDS reuse
        const float C = 8000000.0f / S;
        invC = S / 8000000.0f;
        #pragma unroll
        for (int d = 0; d < 4; ++d) {
            unsigned p0 = 0, p1 = 0, p2 = 0;
            #pragma unroll
            for (int jj = 0; jj < 4; ++jj) {
                int q  = __float2int_rn(wv[d * 4 + jj] * C);
                int d2 = (q << 24) >> 24;          // sext low byte
                int r1 = (q - d2) >> 8;            // exact (divisible)
                int d1 = (r1 << 24) >> 24;
                int d0 = (r1 - d1) >> 8;           // |d0| <= 123
                p0 |= (unsigned)(d0 & 0xFF) << (8 * jj);
                p1 |= (unsigned)(d1 & 0xFF) << (8 * jj);
                p2 |= (unsigned)(d2 & 0xFF) << (8 * jj);
            }
            wi0[d] = (int)p0; wi1[d] = (int)p1; wi2[d] = (int)p2;
        }
    }

    // ---- LIF state (wq==0 wave), C-layout: b = b0+lq*4+r, g = gw+mrow
    float v[4]  = {0.f, 0.f, 0.f, 0.f};
    float cu[4] = {0.f, 0.f, 0.f, 0.f};
    float zf[4] = {0.f, 0.f, 0.f, 0.f};

    // A-frag source: 16 consecutive bytes at row b0+mrow, col wq*64+lq*16
    const unsigned char* ap = a8 + (size_t)(b0 + mrow) * F_DIM + wq * 64 + lq * 16;

    auto ldA = [&](int t) -> int4v {
        return *(const int4v*)(ap + (size_t)t * BF);
    };

    const int4v iz = {0, 0, 0, 0};

    // 3 exact-int MFMAs + combine to fp32 M = acc0*2^16 + acc1*2^8 + acc2
    auto mfma_combine = [&](int4v aI) -> floatx4 {
        int4v acc0 = __builtin_amdgcn_mfma_i32_16x16x64_i8(aI, wi0, iz, 0, 0, 0);
        int4v acc1 = __builtin_amdgcn_mfma_i32_16x16x64_i8(aI, wi1, iz, 0, 0, 0);
        int4v acc2 = __builtin_amdgcn_mfma_i32_16x16x64_i8(aI, wi2, iz, 0, 0, 0);
        floatx4 M;
        #pragma unroll
        for (int r = 0; r < 4; ++r) {
            int a12 = (acc1[r] << 8) + acc2[r];          // exact int (<2^25)
            M[r] = fmaf((float)acc0[r], 65536.0f, (float)a12);
        }
        return M;
    };

    auto lif_step = [&](const floatx4& Mown, const float* xb) {
        floatx4 s = Mown;
        #pragma unroll
        for (int j = 0; j < 7; ++j) {
            floatx4 p = *(const floatx4*)(xb + j * 256 + lane * 4);
            #pragma unroll
            for (int r = 0; r < 4; ++r) s[r] += p[r];
        }
        #pragma unroll
        for (int r = 0; r < 4; ++r) {
            float x    = s[r] * invC;
            float vdec = v[r] + 0.1f * ((0.0f - v[r]) + cu[r]);  // DT*TAU_MEM_INV
            float idec = cu[r] - 0.2f * cu[r];                    // DT*TAU_SYN_INV
            bool  spk  = (vdec - 1.0f) > 0.0f;                    // heaviside
            zf[r] = spk ? 1.0f : 0.0f;
            v[r]  = spk ? 0.0f : vdec;                            // V_RESET = 0
            cu[r] = idec + x;
        }
    };

    floatx4 MA = {0.f, 0.f, 0.f, 0.f};   // even-t combined partial (wq0)
    floatx4 MB = {0.f, 0.f, 0.f, 0.f};   // odd-t combined partial (wq0)

    int4v aA = ldA(0);
    int4v aB = ldA(1);

    for (int t = 0; t < T_STEPS; t += 2) {
        // ======== even: compute t ========
        if (wq == 0 && t > 0)
            lif_step(MB, &xbuf[1][0]);              // LIF(t-1), reads xbuf[1]
        {
            int4v aI = aA;
            if (t + 2 < T_STEPS) aA = ldA(t + 2);
            floatx4 M = mfma_combine(aI);
            if (wq > 0) *(floatx4*)&xbuf[0][(wq - 1) * 256 + lane * 4] = M;
            else        MA = M;
        }
        __syncthreads();   // xbuf[0] ready; xbuf[1] reads done

        // ======== odd: compute t+1 ========
        if (wq == 0)
            lif_step(MA, &xbuf[0][0]);              // LIF(t), reads xbuf[0]
        {
            int4v aI = aB;
            if (t + 3 < T_STEPS) aB = ldA(t + 3);
            floatx4 M = mfma_combine(aI);
            if (wq > 0) *(floatx4*)&xbuf[1][(wq - 1) * 256 + lane * 4] = M;
            else        MB = M;
        }
        __syncthreads();   // xbuf[1] ready; xbuf[0] reads done
    }
    // epilogue: LIF(1023) from odd partials
    if (wq == 0) {
        lif_step(MB, &xbuf[1][0]);
        #pragma unroll
        for (int r = 0; r < 4; ++r) {
            const size_t idx = (size_t)(b0 + lq * 4 + r) * F_DIM + gw + mrow;
            out[idx]          = zf[r];
            out[BF + idx]     = v[r];
            out[2 * BF + idx] = cu[r];
        }
    }
}

// -------- R9 main kernel (verified): bits input, in-loop expand ---------
__global__ __launch_bounds__(512, 4)
void lif_kernel_bits(const unsigned* __restrict__ bits,
                     const float* __restrict__ W,
                     float* __restrict__ out)
{
    __shared__ float xbuf[2][7 * 256];
    __shared__ float rowmax[8][16];

    const int tid  = threadIdx.x;
    const int lane = tid & 63;
    const int wq   = tid >> 6;
    const int bt   = blockIdx.x & 15;
    const int gb   = blockIdx.x >> 4;
    const int b0   = bt * 16;
    const int gw   = gb * 16;
    const int mrow = lane & 15;
    const int lq   = lane >> 4;

    int4v wi0, wi1, wi2;
    float invC;
    {
        const float* wp = W + (size_t)(gw + mrow) * F_DIM + wq * 64 + lq * 16;
        float wv[16];
        float lm = 0.0f;
        #pragma unroll
        for (int j = 0; j < 16; ++j) {
            wv[j] = wp[j];
            lm = fmaxf(lm, fabsf(wv[j]));
        }
        lm = fmaxf(lm, __shfl_xor(lm, 16, 64));
        lm = fmaxf(lm, __shfl_xor(lm, 32, 64));
        if (lane < 16) rowmax[wq][lane] = lm;
        __syncthreads();
        float S = 1e-30f;
        #pragma unroll
        for (int w8 = 0; w8 < 8; ++w8) S = fmaxf(S, rowmax[w8][mrow]);
        __syncthreads();
        const float C = 8000000.0f / S;
        invC = S / 8000000.0f;
        #pragma unroll
        for (int d = 0; d < 4; ++d) {
            unsigned p0 = 0, p1 = 0, p2 = 0;
            #pragma unroll
            for (int jj = 0; jj < 4; ++jj) {
                int q  = __float2int_rn(wv[d * 4 + jj] * C);
                int d2 = (q << 24) >> 24;
                int r1 = (q - d2) >> 8;
                int d1 = (r1 << 24) >> 24;
                int d0 = (r1 - d1) >> 8;
                p0 |= (unsigned)(d0 & 0xFF) << (8 * jj);
                p1 |= (unsigned)(d1 & 0xFF) << (8 * jj);
                p2 |= (unsigned)(d2 & 0xFF) << (8 * jj);
            }
            wi0[d] = (int)p0; wi1[d] = (int)p1; wi2[d] = (int)p2;
        }
    }

    float v[4]  = {0.f, 0.f, 0.f, 0.f};
    float cu[4] = {0.f, 0.f, 0.f, 0.f};
    float zf[4] = {0.f, 0.f, 0.f, 0.f};

    const unsigned* bp = bits + (size_t)(b0 + mrow) * 16 + wq * 2;

    auto ldbits = [&](int t) -> uintx2 {
        return *(const uintx2*)(bp + (size_t)t * 4096);
    };

    auto expand = [&](uintx2 bq) -> int4v {
        unsigned h16 = ((lq & 2) ? bq[1] : bq[0]) >> ((lq & 1) * 16);
        int4v a;
        #pragma unroll
        for (int d = 0; d < 4; ++d) {
            unsigned b4 = (h16 >> (4 * d)) & 0xFu;
            unsigned u  = (b4 << 7) + b4;
            u = (b4 << 14) + u;
            u = (b4 << 21) + u;
            a[d] = (int)(u & 0x01010101u);
        }
        return a;
    };

    const int4v iz = {0, 0, 0, 0};

    auto mfma_combine = [&](int4v aI) -> floatx4 {
        int4v acc0 = __builtin_amdgcn_mfma_i32_16x16x64_i8(aI, wi0, iz, 0, 0, 0);
        int4v acc1 = __builtin_amdgcn_mfma_i32_16x16x64_i8(aI, wi1, iz, 0, 0, 0);
        int4v acc2 = __builtin_amdgcn_mfma_i32_16x16x64_i8(aI, wi2, iz, 0, 0, 0);
        floatx4 M;
        #pragma unroll
        for (int r = 0; r < 4; ++r) {
            int a12 = (acc1[r] << 8) + acc2[r];
            M[r] = fmaf((float)acc0[r], 65536.0f, (float)a12);
        }
        return M;
    };

    auto lif_step = [&](const floatx4& Mown, const float* xb) {
        floatx4 s = Mown;
        #pragma unroll
        for (int j = 0; j < 7; ++j) {
            floatx4 p = *(const floatx4*)(xb + j * 256 + lane * 4);
            #pragma unroll
            for (int r = 0; r < 4; ++r) s[r] += p[r];
        }
        #pragma unroll
        for (int r = 0; r < 4; ++r) {
            float x    = s[r] * invC;
            float vdec = v[r] + 0.1f * ((0.0f - v[r]) + cu[r]);
            float idec = cu[r] - 0.2f * cu[r];
            bool  spk  = (vdec - 1.0f) > 0.0f;
            zf[r] = spk ? 1.0f : 0.0f;
            v[r]  = spk ? 0.0f : vdec;
            cu[r] = idec + x;
        }
    };

    floatx4 MA = {0.f, 0.f, 0.f, 0.f};
    floatx4 MB = {0.f, 0.f, 0.f, 0.f};

    uintx2 bqA = ldbits(0);
    uintx2 bqB = ldbits(1);

    for (int t = 0; t < T_STEPS; t += 2) {
        if (wq == 0 && t > 0)
            lif_step(MB, &xbuf[1][0]);
        {
            int4v aI = expand(bqA);
            if (t + 2 < T_STEPS) bqA = ldbits(t + 2);
            floatx4 M = mfma_combine(aI);
            if (wq > 0) *(floatx4*)&xbuf[0][(wq - 1) * 256 + lane * 4] = M;
            else        MA = M;
        }
        __syncthreads();

        if (wq == 0)
            lif_step(MA, &xbuf[0][0]);
        {
            int4v aI = expand(bqB);
            if (t + 3 < T_STEPS) bqB = ldbits(t + 3);
            floatx4 M = mfma_combine(aI);
            if (wq > 0) *(floatx4*)&xbuf[1][(wq - 1) * 256 + lane * 4] = M;
            else        MB = M;
        }
        __syncthreads();
    }
    if (wq == 0) {
        lif_step(MB, &xbuf[1][0]);
        #pragma unroll
        for (int r = 0; r < 4; ++r) {
            const size_t idx = (size_t)(b0 + lq * 4 + r) * F_DIM + gw + mrow;
            out[idx]          = zf[r];
            out[BF + idx]     = v[r];
            out[2 * BF + idx] = cu[r];
        }
    }
}

// ---------------- fallback: R3 fp32-input kernel (verified) ----------------
__global__ __launch_bounds__(256, 1)
void lif_kernel_f32(const float* __restrict__ spikes,
                    const float* __restrict__ W,
                    float* __restrict__ out)
{
    __shared__ unsigned short sAf[16 * ROWP];
    __shared__ float xbuf[2 * 256];

    const int tid  = threadIdx.x;
    const int lane = tid & 63;
    const int w    = tid >> 6;
    const int gh   = w & 1;
    const int kh   = w >> 1;
    const int bt   = blockIdx.x & 15;
    const int gb   = blockIdx.x >> 4;
    const int b0   = bt * 16;
    const int gw   = gb * 32 + gh * 16;
    const int mrow = lane & 15;
    const int kq   = lane >> 4;

    short8 whi[8], wmd[8], wlo[8];
    {
        const float* wp = W + (size_t)(gw + mrow) * F_DIM + kh * 256 + kq * 8;
        #pragma unroll
        for (int ks = 0; ks < 8; ++ks) {
            short8 hi, md, lo;
            #pragma unroll
            for (int j = 0; j < 8; ++j) {
                float f = wp[ks * 32 + j];
                unsigned short h = f2bf_rne(f);
                float r1 = f - bf2f(h);
                unsigned short m = f2bf_rne(r1);
                float r2 = r1 - bf2f(m);
                hi[j] = (short)h;
                md[j] = (short)m;
                lo[j] = (short)f2bf_rne(r2);
            }
            whi[ks] = hi; wmd[ks] = md; wlo[ks] = lo;
        }
    }

    float v[4]  = {0.f, 0.f, 0.f, 0.f};
    float cu[4] = {0.f, 0.f, 0.f, 0.f};
    float zf[4] = {0.f, 0.f, 0.f, 0.f};

    floatx4 ld[8];
    auto issue_loads = [&](int t) {
        const floatx4* sp = (const floatx4*)(spikes + (size_t)t * BF + (size_t)b0 * F_DIM);
        #pragma unroll
        for (int j = 0; j < 8; ++j)
            ld[j] = sp[tid + 256 * j];
    };

    issue_loads(0);
    for (int t = 0; t < T_STEPS; ++t) {
        #pragma unroll
        for (int j = 0; j < 8; ++j) {
            const int q = tid + 256 * j;
            const int row = q >> 7, col4 = q & 127;
            unsigned u0 = __float_as_uint(ld[j][0]);
            unsigned u1 = __float_as_uint(ld[j][1]);
            unsigned u2 = __float_as_uint(ld[j][2]);
            unsigned u3 = __float_as_uint(ld[j][3]);
            uintx2 d;
            d[0] = (u0 >> 16) | (u1 & 0xFFFF0000u);
            d[1] = (u2 >> 16) | (u3 & 0xFFFF0000u);
            *(uintx2*)&sAf[row * ROWP + col4 * 4] = d;
        }
        __syncthreads();
        if (t + 1 < T_STEPS) issue_loads(t + 1);

        floatx4 ah = {0.f, 0.f, 0.f, 0.f};
        floatx4 am = {0.f, 0.f, 0.f, 0.f};
        floatx4 al = {0.f, 0.f, 0.f, 0.f};
        const unsigned short* arow = &sAf[mrow * ROWP + kh * 256 + kq * 8];
        #pragma unroll
        for (int ks = 0; ks < 8; ++ks) {
            short8 a = *(const short8*)(arow + ks * 32);
            ah = __builtin_amdgcn_mfma_f32_16x16x32_bf16(a, whi[ks], ah, 0, 0, 0);
            am = __builtin_amdgcn_mfma_f32_16x16x32_bf16(a, wmd[ks], am, 0, 0, 0);
            al = __builtin_amdgcn_mfma_f32_16x16x32_bf16(a, wlo[ks], al, 0, 0, 0);
        }

        if (kh == 1) {
            floatx4 xp = (ah + am) + al;
            *(floatx4*)&xbuf[gh * 256 + lane * 4] = xp;
        }
        __syncthreads();
        if (kh == 0) {
            floatx4 other = *(const floatx4*)&xbuf[gh * 256 + lane * 4];
            #pragma unroll
            for (int r = 0; r < 4; ++r) {
                float x    = ((ah[r] + am[r]) + al[r]) + other[r];
                float vdec = v[r] + 0.1f * ((0.0f - v[r]) + cu[r]);
                float idec = cu[r] - 0.2f * cu[r];
                bool  spk  = (vdec - 1.0f) > 0.0f;
                zf[r] = spk ? 1.0f : 0.0f;
                v[r]  = spk ? 0.0f : vdec;
                cu[r] = idec + x;
            }
        }
    }

    if (kh == 0) {
        #pragma unroll
        for (int r = 0; r < 4; ++r) {
            const size_t idx = (size_t)(b0 + kq * 4 + r) * F_DIM + gw + mrow;
            out[idx]          = zf[r];
            out[BF + idx]     = v[r];
            out[2 * BF + idx] = cu[r];
        }
    }
}

extern "C" void kernel_launch(void* const* d_in, const int* in_sizes, int n_in,
                              void* d_out, int out_size, void* d_ws, size_t ws_size,
                              hipStream_t stream)
{
    const float* spikes = (const float*)d_in[0];   // [T,B,F] fp32
    const float* W      = (const float*)d_in[1];   // [F,F]   fp32
    float* out          = (float*)d_out;           // [3,B,F] fp32

    const size_t need_i8   = (size_t)T_STEPS * BF;                    // 128 MiB
    const size_t need_bits = (size_t)T_STEPS * B_DIM * (F_DIM / 8);   // 16 MiB

    if (d_ws != nullptr && ws_size >= need_i8) {
        unsigned char* a8 = (unsigned char*)d_ws;
        pack_i8_kernel<<<dim3(2048), dim3(256), 0, stream>>>(spikes, (uintx4*)a8);
        lif_kernel_i8<<<dim3(512), dim3(512), 0, stream>>>(a8, W, out);
    } else if (d_ws != nullptr && ws_size >= need_bits) {
        unsigned* bits = (unsigned*)d_ws;
        pack_kernel<<<dim3(2048), dim3(256), 0, stream>>>(spikes, bits);
        lif_kernel_bits<<<dim3(512), dim3(512), 0, stream>>>(bits, W, out);
    } else {
        lif_kernel_f32<<<dim3(256), dim3(256), 0, stream>>>(spikes, W, out);
    }
}

// Round 8
// 1159.731 us; speedup vs baseline: 1.0742x; 1.0742x over previous
//
#include <hip/hip_runtime.h>
#include <hip/hip_bf16.h>

// LIF fused kernel, Round 11: 2 g-tiles per wave (shared A-expand), i8 engine.
//
// R10 post-mortem: pre-expanded 128MB i8 slab traded VALU (62->38%) for
// L3/HBM stalls (FETCH 12->70MB, slower net). REVERT to L2-resident 16MB
// bits + in-register expand (R9 = 506us), and cut VALU structurally:
//
// R11: chip-wide, A is expanded once per g-tile = 32x redundant in R9.
// Here each wave computes ng=2 g-tiles from ONE expanded A-frag:
//   per wave/t: 1 expand + 6 independent MFMA + 2 int-combines.
// Block = 8 K-eighth waves x 32 g-cols; grid 256 = 16bt x 16gb2 (1/CU,
// 2 waves/SIMD). LIF finisher split: wq0 -> tile0, wq1 -> tile1.
// Micro: expand via b4*0x204081 & 0x01010101 (mul_u24); combine as exact
// int (a0<<16)+(a1<<8)+a2 then 1 cvt (bit-identical to R9's fma: the
// product a0*65536 was exact, single rounding either way). Tile1 partial
// sum ordered wq0-first to match R9's order -> absmax should reproduce
// 0.0078125 exactly.
//
// Packed layout: bits[t*4096 + b*16 + wd], bit j (LSB) = spike[t][b][wd*32+j].

typedef __attribute__((ext_vector_type(8))) short short8;   // 8 x bf16
typedef __attribute__((ext_vector_type(4))) float floatx4;
typedef __attribute__((ext_vector_type(2))) unsigned uintx2;
typedef __attribute__((ext_vector_type(4))) int int4v;

#define T_STEPS 1024
#define B_DIM   256
#define F_DIM   512
#define BF      (B_DIM * F_DIM)
#define ROWP    520   // (fallback kernel only)

static __device__ __forceinline__ unsigned short f2bf_rne(float f) {
    unsigned u = __float_as_uint(f);
    return (unsigned short)((u + 0x7FFFu + ((u >> 16) & 1u)) >> 16);
}
static __device__ __forceinline__ float bf2f(unsigned short h) {
    return __uint_as_float(((unsigned)h) << 16);
}

// ---------------- prepass: fp32 {0,1} -> bitmask ----------------
__global__ __launch_bounds__(256)
void pack_kernel(const float* __restrict__ sp, unsigned* __restrict__ bits)
{
    const int lane = threadIdx.x & 63;
    const int wv   = blockIdx.x * 4 + (threadIdx.x >> 6);
    for (int c = wv; c < 65536; c += 2048 * 4) {
        const float* p = sp + (size_t)c * 2048;
        unsigned val = 0;
        #pragma unroll
        for (int r = 0; r < 32; ++r) {
            float x = p[r * 64 + lane];
            unsigned long long m = __ballot(x != 0.0f);
            unsigned sel = (lane & 1) ? (unsigned)(m >> 32) : (unsigned)m;
            if ((lane >> 1) == r) val = sel;
        }
        bits[(size_t)c * 64 + lane] = val;
    }
}

// -------- main kernel: 2 g-tiles/wave, 8 K-eighth waves, 256 blocks -----
__global__ __launch_bounds__(512, 2)
void lif_kernel_bits(const unsigned* __restrict__ bits,
                     const float* __restrict__ W,
                     float* __restrict__ out)
{
    __shared__ float xbuf[2][2][7 * 256];   // [dbuf][tile][slot 0..6][16x16]
    __shared__ float rowmax[8][32];         // setup-only

    const int tid  = threadIdx.x;
    const int lane = tid & 63;
    const int wq   = tid >> 6;          // 0..7: K-eighth, k in [wq*64, +64)
    const int bt   = blockIdx.x & 15;
    const int gb2  = blockIdx.x >> 4;   // 0..15
    const int b0   = bt * 16;
    const int gw   = gb2 * 32;          // block covers g in [gw, gw+32)
    const int mrow = lane & 15;
    const int lq   = lane >> 4;         // 0..3: k-chunk of 16 within the 64

    // ---- W setup (once), both tiles: rows gw+t2*16+mrow, k = wq*64+lq*16+j
    int4v wiA0, wiA1, wiA2, wiB0, wiB1, wiB2;
    float invC0, invC1;
    {
        float wva[16], wvb[16];
        auto loadmax = [&](int t2, float* wv) {
            const float* wp = W + (size_t)(gw + t2 * 16 + mrow) * F_DIM + wq * 64 + lq * 16;
            float lm = 0.0f;
            #pragma unroll
            for (int j = 0; j < 16; ++j) {
                wv[j] = wp[j];
                lm = fmaxf(lm, fabsf(wv[j]));
            }
            lm = fmaxf(lm, __shfl_xor(lm, 16, 64));
            lm = fmaxf(lm, __shfl_xor(lm, 32, 64));
            if (lane < 16) rowmax[wq][t2 * 16 + lane] = lm;
        };
        loadmax(0, wva);
        loadmax(1, wvb);
        __syncthreads();
        auto quant = [&](int t2, const float* wv, int4v& w0, int4v& w1, int4v& w2) -> float {
            float S = 1e-30f;
            #pragma unroll
            for (int w8 = 0; w8 < 8; ++w8) S = fmaxf(S, rowmax[w8][t2 * 16 + mrow]);
            const float C = 8000000.0f / S;
            #pragma unroll
            for (int d = 0; d < 4; ++d) {
                unsigned p0 = 0, p1 = 0, p2 = 0;
                #pragma unroll
                for (int jj = 0; jj < 4; ++jj) {
                    int q  = __float2int_rn(wv[d * 4 + jj] * C);
                    int d2 = (q << 24) >> 24;          // sext low byte
                    int r1 = (q - d2) >> 8;            // exact (divisible)
                    int d1 = (r1 << 24) >> 24;
                    int d0 = (r1 - d1) >> 8;           // |d0| <= 123
                    p0 |= (unsigned)(d0 & 0xFF) << (8 * jj);
                    p1 |= (unsigned)(d1 & 0xFF) << (8 * jj);
                    p2 |= (unsigned)(d2 & 0xFF) << (8 * jj);
                }
                w0[d] = (int)p0; w1[d] = (int)p1; w2[d] = (int)p2;
            }
            return S / 8000000.0f;
        };
        invC0 = quant(0, wva, wiA0, wiA1, wiA2);
        invC1 = quant(1, wvb, wiB0, wiB1, wiB2);
        __syncthreads();   // rowmax consumed
    }

    // ---- LIF state: wq0 owns tile0 (g=gw+mrow), wq1 owns tile1 (g=gw+16+mrow)
    float v[4]  = {0.f, 0.f, 0.f, 0.f};
    float cu[4] = {0.f, 0.f, 0.f, 0.f};
    float zf[4] = {0.f, 0.f, 0.f, 0.f};

    // bits source: row b0+mrow, dwords wq*2, wq*2+1 (8B aligned)
    const unsigned* bp = bits + (size_t)(b0 + mrow) * 16 + wq * 2;  // +4096/t

    auto ldbits = [&](int t) -> uintx2 {
        return *(const uintx2*)(bp + (size_t)t * 4096);
    };

    // expand 16 bits -> 16 i8 bytes {0,1}: per dword b4 * 0x204081 spreads
    // bit j to byte j (no carries, b4<=15); mask keeps LSBs.
    auto expand = [&](uintx2 bq) -> int4v {
        unsigned h16 = ((lq & 2) ? bq[1] : bq[0]) >> ((lq & 1) * 16);
        int4v a;
        #pragma unroll
        for (int d = 0; d < 4; ++d) {
            unsigned b4 = (h16 >> (4 * d)) & 0xFu;
            a[d] = (int)((b4 * 0x00204081u) & 0x01010101u);
        }
        return a;
    };

    const int4v iz = {0, 0, 0, 0};

    // 3 exact-int MFMAs + exact-int combine + 1 cvt per element
    auto mc = [&](int4v aI, int4v w0, int4v w1, int4v w2) -> floatx4 {
        int4v a0 = __builtin_amdgcn_mfma_i32_16x16x64_i8(aI, w0, iz, 0, 0, 0);
        int4v a1 = __builtin_amdgcn_mfma_i32_16x16x64_i8(aI, w1, iz, 0, 0, 0);
        int4v a2 = __builtin_amdgcn_mfma_i32_16x16x64_i8(aI, w2, iz, 0, 0, 0);
        floatx4 M;
        #pragma unroll
        for (int r = 0; r < 4; ++r)
            M[r] = (float)(((a0[r] << 16) + (a1[r] << 8)) + a2[r]);  // |.|<2^30 exact
        return M;
    };

    // finisher LIF. t1ord=false: sum = own(wq0) + slots0..6 (wq1..7) [R9 order].
    // t1ord=true (tile1, own=wq1): sum = slot0(wq0) + own + slots1..6 (wq2..7).
    auto lif_step = [&](floatx4 Mown, const float* xb, float ic, bool t1ord) {
        floatx4 s;
        int j0;
        if (!t1ord) {
            s = Mown;
            j0 = 0;
        } else {
            s = *(const floatx4*)(xb + lane * 4);
            #pragma unroll
            for (int r = 0; r < 4; ++r) s[r] += Mown[r];
            j0 = 1;
        }
        for (int j = j0; j < 7; ++j) {
            floatx4 p = *(const floatx4*)(xb + j * 256 + lane * 4);
            #pragma unroll
            for (int r = 0; r < 4; ++r) s[r] += p[r];
        }
        #pragma unroll
        for (int r = 0; r < 4; ++r) {
            float x    = s[r] * ic;
            float vdec = v[r] + 0.1f * ((0.0f - v[r]) + cu[r]);  // DT*TAU_MEM_INV
            float idec = cu[r] - 0.2f * cu[r];                    // DT*TAU_SYN_INV
            bool  spk  = (vdec - 1.0f) > 0.0f;                    // heaviside
            zf[r] = spk ? 1.0f : 0.0f;
            v[r]  = spk ? 0.0f : vdec;                            // V_RESET = 0
            cu[r] = idec + x;
        }
    };

    // partial-slot byte offsets (floats)
    const int s0i = (wq - 1) * 256 + lane * 4;                    // tile0, wq>=1
    const int s1i = ((wq == 0) ? 0 : (wq - 1)) * 256 + lane * 4;  // tile1, wq!=1

    const floatx4 fz = {0.f, 0.f, 0.f, 0.f};
    floatx4 MA = fz, MB = fz;   // finisher own-partials (even/odd t)

    uintx2 bqA = ldbits(0);
    uintx2 bqB = ldbits(1);

    for (int t = 0; t < T_STEPS; t += 2) {
        // ======== even: compute t; deferred LIF(t-1) ========
        if (t > 0) {
            if (wq == 0)      lif_step(MB, &xbuf[1][0][0], invC0, false);
            else if (wq == 1) lif_step(MB, &xbuf[1][1][0], invC1, true);
        }
        {
            int4v aI = expand(bqA);
            if (t + 2 < T_STEPS) bqA = ldbits(t + 2);
            floatx4 M0 = mc(aI, wiA0, wiA1, wiA2);
            floatx4 M1 = mc(aI, wiB0, wiB1, wiB2);
            if (wq != 0) *(floatx4*)&xbuf[0][0][s0i] = M0;
            if (wq != 1) *(floatx4*)&xbuf[0][1][s1i] = M1;
            MA = (wq == 0) ? M0 : M1;
        }
        __syncthreads();   // xbuf[0] ready; xbuf[1] reads done

        // ======== odd: compute t+1; LIF(t) ========
        if (wq == 0)      lif_step(MA, &xbuf[0][0][0], invC0, false);
        else if (wq == 1) lif_step(MA, &xbuf[0][1][0], invC1, true);
        {
            int4v aI = expand(bqB);
            if (t + 3 < T_STEPS) bqB = ldbits(t + 3);
            floatx4 M0 = mc(aI, wiA0, wiA1, wiA2);
            floatx4 M1 = mc(aI, wiB0, wiB1, wiB2);
            if (wq != 0) *(floatx4*)&xbuf[1][0][s0i] = M0;
            if (wq != 1) *(floatx4*)&xbuf[1][1][s1i] = M1;
            MB = (wq == 0) ? M0 : M1;
        }
        __syncthreads();   // xbuf[1] ready; xbuf[0] reads done
    }
    // epilogue: LIF(1023) from odd partials, then store
    if (wq == 0)      lif_step(MB, &xbuf[1][0][0], invC0, false);
    else if (wq == 1) lif_step(MB, &xbuf[1][1][0], invC1, true);
    if (wq < 2) {
        const int gg = gw + wq * 16 + mrow;
        #pragma unroll
        for (int r = 0; r < 4; ++r) {
            const size_t idx = (size_t)(b0 + lq * 4 + r) * F_DIM + gg;
            out[idx]          = zf[r];
            out[BF + idx]     = v[r];
            out[2 * BF + idx] = cu[r];
        }
    }
}

// ---------------- fallback: R3 fp32-input kernel (verified) ----------------
__global__ __launch_bounds__(256, 1)
void lif_kernel_f32(const float* __restrict__ spikes,
                    const float* __restrict__ W,
                    float* __restrict__ out)
{
    __shared__ unsigned short sAf[16 * ROWP];
    __shared__ float xbuf[2 * 256];

    const int tid  = threadIdx.x;
    const int lane = tid & 63;
    const int w    = tid >> 6;
    const int gh   = w & 1;
    const int kh   = w >> 1;
    const int bt   = blockIdx.x & 15;
    const int gb   = blockIdx.x >> 4;
    const int b0   = bt * 16;
    const int gw   = gb * 32 + gh * 16;
    const int mrow = lane & 15;
    const int kq   = lane >> 4;

    short8 whi[8], wmd[8], wlo[8];
    {
        const float* wp = W + (size_t)(gw + mrow) * F_DIM + kh * 256 + kq * 8;
        #pragma unroll
        for (int ks = 0; ks < 8; ++ks) {
            short8 hi, md, lo;
            #pragma unroll
            for (int j = 0; j < 8; ++j) {
                float f = wp[ks * 32 + j];
                unsigned short h = f2bf_rne(f);
                float r1 = f - bf2f(h);
                unsigned short m = f2bf_rne(r1);
                float r2 = r1 - bf2f(m);
                hi[j] = (short)h;
                md[j] = (short)m;
                lo[j] = (short)f2bf_rne(r2);
            }
            whi[ks] = hi; wmd[ks] = md; wlo[ks] = lo;
        }
    }

    float v[4]  = {0.f, 0.f, 0.f, 0.f};
    float cu[4] = {0.f, 0.f, 0.f, 0.f};
    float zf[4] = {0.f, 0.f, 0.f, 0.f};

    floatx4 ld[8];
    auto issue_loads = [&](int t) {
        const floatx4* sp = (const floatx4*)(spikes + (size_t)t * BF + (size_t)b0 * F_DIM);
        #pragma unroll
        for (int j = 0; j < 8; ++j)
            ld[j] = sp[tid + 256 * j];
    };

    issue_loads(0);
    for (int t = 0; t < T_STEPS; ++t) {
        #pragma unroll
        for (int j = 0; j < 8; ++j) {
            const int q = tid + 256 * j;
            const int row = q >> 7, col4 = q & 127;
            unsigned u0 = __float_as_uint(ld[j][0]);
            unsigned u1 = __float_as_uint(ld[j][1]);
            unsigned u2 = __float_as_uint(ld[j][2]);
            unsigned u3 = __float_as_uint(ld[j][3]);
            uintx2 d;
            d[0] = (u0 >> 16) | (u1 & 0xFFFF0000u);
            d[1] = (u2 >> 16) | (u3 & 0xFFFF0000u);
            *(uintx2*)&sAf[row * ROWP + col4 * 4] = d;
        }
        __syncthreads();
        if (t + 1 < T_STEPS) issue_loads(t + 1);

        floatx4 ah = {0.f, 0.f, 0.f, 0.f};
        floatx4 am = {0.f, 0.f, 0.f, 0.f};
        floatx4 al = {0.f, 0.f, 0.f, 0.f};
        const unsigned short* arow = &sAf[mrow * ROWP + kh * 256 + kq * 8];
        #pragma unroll
        for (int ks = 0; ks < 8; ++ks) {
            short8 a = *(const short8*)(arow + ks * 32);
            ah = __builtin_amdgcn_mfma_f32_16x16x32_bf16(a, whi[ks], ah, 0, 0, 0);
            am = __builtin_amdgcn_mfma_f32_16x16x32_bf16(a, wmd[ks], am, 0, 0, 0);
            al = __builtin_amdgcn_mfma_f32_16x16x32_bf16(a, wlo[ks], al, 0, 0, 0);
        }

        if (kh == 1) {
            floatx4 xp = (ah + am) + al;
            *(floatx4*)&xbuf[gh * 256 + lane * 4] = xp;
        }
        __syncthreads();
        if (kh == 0) {
            floatx4 other = *(const floatx4*)&xbuf[gh * 256 + lane * 4];
            #pragma unroll
            for (int r = 0; r < 4; ++r) {
                float x    = ((ah[r] + am[r]) + al[r]) + other[r];
                float vdec = v[r] + 0.1f * ((0.0f - v[r]) + cu[r]);
                float idec = cu[r] - 0.2f * cu[r];
                bool  spk  = (vdec - 1.0f) > 0.0f;
                zf[r] = spk ? 1.0f : 0.0f;
                v[r]  = spk ? 0.0f : vdec;
                cu[r] = idec + x;
            }
        }
    }

    if (kh == 0) {
        #pragma unroll
        for (int r = 0; r < 4; ++r) {
            const size_t idx = (size_t)(b0 + kq * 4 + r) * F_DIM + gw + mrow;
            out[idx]          = zf[r];
            out[BF + idx]     = v[r];
            out[2 * BF + idx] = cu[r];
        }
    }
}

extern "C" void kernel_launch(void* const* d_in, const int* in_sizes, int n_in,
                              void* d_out, int out_size, void* d_ws, size_t ws_size,
                              hipStream_t stream)
{
    const float* spikes = (const float*)d_in[0];   // [T,B,F] fp32
    const float* W      = (const float*)d_in[1];   // [F,F]   fp32
    float* out          = (float*)d_out;           // [3,B,F] fp32

    const size_t need_bits = (size_t)T_STEPS * B_DIM * (F_DIM / 8);   // 16 MiB

    if (d_ws != nullptr && ws_size >= need_bits) {
        unsigned* bits = (unsigned*)d_ws;
        pack_kernel<<<dim3(2048), dim3(256), 0, stream>>>(spikes, bits);
        lif_kernel_bits<<<dim3(256), dim3(512), 0, stream>>>(bits, W, out);
    } else {
        lif_kernel_f32<<<dim3(256), dim3(256), 0, stream>>>(spikes, W, out);
    }
}

// Round 9
// 1071.629 us; speedup vs baseline: 1.1625x; 1.0822x over previous
//
#include <hip/hip_runtime.h>
#include <hip/hip_bf16.h>

// LIF fused kernel, Round 12: R9 geometry + int-exact xbuf + 1 barrier/2t
//                             + split finisher (wq0: r01, wq1: r23).
//
// R11 post-mortem: tile-sharing cut VALU (62->49%) but halved occupancy ->
// idle grew, net neutral. R9 config (grid 512, 8 K-eighth waves, 4 w/SIMD,
// 506us) is the best measured; R12 keeps it and removes residuals:
//  1. Producers write EXACT-INT combine (a0<<16)+(a1<<8)+a2 to xbuf (no
//     cvt); finisher sums 8 ints exactly (order-free; |sum| <= 1.2e9 hard
//     bound, no overflow) then ONE cvt + invC mul per element.
//  2. Barrier per 2 t: 4-slot xbuf (t&3). Finisher reads slots (t-2)&3,
//     (t-1)&3; producers write t&3,(t+1)&3 -- disjoint; pair-end barrier
//     gives both orderings.
//  3. Finisher duty split by accumulator rows: wq0 handles r=0,1; wq1
//     r=2,3 (LIF state stays wave-resident; halves finisher path).
// i8 engine (3-digit W quant, mfma_i32_16x16x64_i8) unchanged from R9.
//
// Packed layout: bits[t*4096 + b*16 + wd], bit j (LSB) = spike[t][b][wd*32+j].

typedef __attribute__((ext_vector_type(8))) short short8;   // 8 x bf16
typedef __attribute__((ext_vector_type(4))) float floatx4;
typedef __attribute__((ext_vector_type(2))) unsigned uintx2;
typedef __attribute__((ext_vector_type(4))) int int4v;

#define T_STEPS 1024
#define B_DIM   256
#define F_DIM   512
#define BF      (B_DIM * F_DIM)
#define ROWP    520   // (fallback kernel only)

static __device__ __forceinline__ unsigned short f2bf_rne(float f) {
    unsigned u = __float_as_uint(f);
    return (unsigned short)((u + 0x7FFFu + ((u >> 16) & 1u)) >> 16);
}
static __device__ __forceinline__ float bf2f(unsigned short h) {
    return __uint_as_float(((unsigned)h) << 16);
}

// ---------------- prepass: fp32 {0,1} -> bitmask ----------------
__global__ __launch_bounds__(256)
void pack_kernel(const float* __restrict__ sp, unsigned* __restrict__ bits)
{
    const int lane = threadIdx.x & 63;
    const int wv   = blockIdx.x * 4 + (threadIdx.x >> 6);
    for (int c = wv; c < 65536; c += 2048 * 4) {
        const float* p = sp + (size_t)c * 2048;
        unsigned val = 0;
        #pragma unroll
        for (int r = 0; r < 32; ++r) {
            float x = p[r * 64 + lane];
            unsigned long long m = __ballot(x != 0.0f);
            unsigned sel = (lane & 1) ? (unsigned)(m >> 32) : (unsigned)m;
            if ((lane >> 1) == r) val = sel;
        }
        bits[(size_t)c * 64 + lane] = val;
    }
}

// -------- main kernel: i8 engine, int xbuf, 1 barrier / 2 t -------------
__global__ __launch_bounds__(512, 4)
void lif_kernel_bits(const unsigned* __restrict__ bits,
                     const float* __restrict__ W,
                     float* __restrict__ out)
{
    __shared__ int   xq[4][8 * 256];   // [t&3][wq*256 + lane*4 + r] int partials
    __shared__ float rowmax[8][16];    // setup-only

    const int tid  = threadIdx.x;
    const int lane = tid & 63;
    const int wq   = tid >> 6;          // 0..7: K-eighth, k in [wq*64, +64)
    const int bt   = blockIdx.x & 15;
    const int gb   = blockIdx.x >> 4;   // 0..31
    const int b0   = bt * 16;
    const int gw   = gb * 16;
    const int mrow = lane & 15;
    const int lq   = lane >> 4;         // 0..3: k-chunk of 16 within the 64

    // ---- W setup (once): rows gw+mrow, k = wq*64 + lq*16 + j  [R9 code]
    int4v wi0, wi1, wi2;
    float invC;
    {
        const float* wp = W + (size_t)(gw + mrow) * F_DIM + wq * 64 + lq * 16;
        float wv[16];
        float lm = 0.0f;
        #pragma unroll
        for (int j = 0; j < 16; ++j) {
            wv[j] = wp[j];
            lm = fmaxf(lm, fabsf(wv[j]));
        }
        lm = fmaxf(lm, __shfl_xor(lm, 16, 64));
        lm = fmaxf(lm, __shfl_xor(lm, 32, 64));
        if (lane < 16) rowmax[wq][lane] = lm;
        __syncthreads();
        float S = 1e-30f;
        #pragma unroll
        for (int w8 = 0; w8 < 8; ++w8) S = fmaxf(S, rowmax[w8][mrow]);
        __syncthreads();   // rowmax consumed before xq activity
        const float C = 8000000.0f / S;
        invC = S / 8000000.0f;
        #pragma unroll
        for (int d = 0; d < 4; ++d) {
            unsigned p0 = 0, p1 = 0, p2 = 0;
            #pragma unroll
            for (int jj = 0; jj < 4; ++jj) {
                int q  = __float2int_rn(wv[d * 4 + jj] * C);
                int d2 = (q << 24) >> 24;          // sext low byte
                int r1 = (q - d2) >> 8;            // exact (divisible)
                int d1 = (r1 << 24) >> 24;
                int d0 = (r1 - d1) >> 8;           // |d0| <= 123
                p0 |= (unsigned)(d0 & 0xFF) << (8 * jj);
                p1 |= (unsigned)(d1 & 0xFF) << (8 * jj);
                p2 |= (unsigned)(d2 & 0xFF) << (8 * jj);
            }
            wi0[d] = (int)p0; wi1[d] = (int)p1; wi2[d] = (int)p2;
        }
    }

    // ---- LIF state: finisher split. wq0 owns r=0,1; wq1 owns r=2,3.
    // neuron (b,g) = (b0 + lq*4 + rbase + rr, gw + mrow), rr in {0,1}.
    const bool fin   = (wq < 2);
    const int  rbase = (wq & 1) * 2;
    float v0 = 0.f, v1 = 0.f, c0 = 0.f, c1 = 0.f, z0 = 0.f, z1 = 0.f;

    // bits source: row b0+mrow, dwords wq*2, wq*2+1 (8B aligned)
    const unsigned* bp = bits + (size_t)(b0 + mrow) * 16 + wq * 2;  // +4096/t

    auto ldbits = [&](int t) -> uintx2 {
        return *(const uintx2*)(bp + (size_t)t * 4096);
    };

    // expand 16 bits -> 16 i8 bytes {0,1}: b4 * 0x204081 spreads bit j to
    // byte j (no carries, b4<=15); mask keeps LSBs.
    auto expand = [&](uintx2 bq) -> int4v {
        unsigned h16 = ((lq & 2) ? bq[1] : bq[0]) >> ((lq & 1) * 16);
        int4v a;
        #pragma unroll
        for (int d = 0; d < 4; ++d) {
            unsigned b4 = (h16 >> (4 * d)) & 0xFu;
            a[d] = (int)((b4 * 0x00204081u) & 0x01010101u);
        }
        return a;
    };

    const int4v iz = {0, 0, 0, 0};

    // 3 exact-int MFMAs + exact-int combine (no cvt; |c| <= 5.2e8)
    auto mci = [&](int4v aI) -> int4v {
        int4v a0 = __builtin_amdgcn_mfma_i32_16x16x64_i8(aI, wi0, iz, 0, 0, 0);
        int4v a1 = __builtin_amdgcn_mfma_i32_16x16x64_i8(aI, wi1, iz, 0, 0, 0);
        int4v a2 = __builtin_amdgcn_mfma_i32_16x16x64_i8(aI, wi2, iz, 0, 0, 0);
        int4v c;
        #pragma unroll
        for (int r = 0; r < 4; ++r)
            c[r] = ((a0[r] << 16) + (a1[r] << 8)) + a2[r];
        return c;
    };

    // finisher: exact-int sum of 8 partials (this wave's r-pair), 1 cvt, LIF
    auto lif2 = [&](const int* xs) {
        int s0 = 0, s1 = 0;
        #pragma unroll
        for (int w8 = 0; w8 < 8; ++w8) {
            const int* p = xs + w8 * 256 + lane * 4 + rbase;
            s0 += p[0];
            s1 += p[1];
        }
        float x0 = (float)s0 * invC;
        float x1 = (float)s1 * invC;
        float vd0 = v0 + 0.1f * ((0.0f - v0) + c0);   // DT*TAU_MEM_INV
        float id0 = c0 - 0.2f * c0;                    // DT*TAU_SYN_INV
        bool  sp0 = (vd0 - 1.0f) > 0.0f;               // heaviside
        z0 = sp0 ? 1.0f : 0.0f;
        v0 = sp0 ? 0.0f : vd0;                         // V_RESET = 0
        c0 = id0 + x0;
        float vd1 = v1 + 0.1f * ((0.0f - v1) + c1);
        float id1 = c1 - 0.2f * c1;
        bool  sp1 = (vd1 - 1.0f) > 0.0f;
        z1 = sp1 ? 1.0f : 0.0f;
        v1 = sp1 ? 0.0f : vd1;
        c1 = id1 + x1;
    };

    uintx2 bqA = ldbits(0);
    uintx2 bqB = ldbits(1);

    for (int t = 0; t < T_STEPS; t += 2) {
        // deferred LIF(t-2), LIF(t-1): slots (t-2)&3 = (t+2)&3, (t+3)&3.
        // These slots are overwritten only NEXT iteration (after barrier).
        if (fin && t > 0) {
            lif2(&xq[(t + 2) & 3][0]);
            lif2(&xq[(t + 3) & 3][0]);
        }
        // produce M(t) -> slot t&3, M(t+1) -> slot (t+1)&3
        {
            int4v cA = mci(expand(bqA));
            *(int4v*)&xq[t & 3][wq * 256 + lane * 4] = cA;
            int4v cB = mci(expand(bqB));
            *(int4v*)&xq[(t + 1) & 3][wq * 256 + lane * 4] = cB;
        }
        if (t + 2 < T_STEPS) {
            bqA = ldbits(t + 2);
            bqB = ldbits(t + 3);
        }
        __syncthreads();   // slots t,t+1 ready; reads of t-2,t-1 done
    }
    // epilogue: LIF(1022) slot 2, LIF(1023) slot 3 (barrier was last stmt)
    if (fin) {
        lif2(&xq[2][0]);
        lif2(&xq[3][0]);
        const int blo = b0 + lq * 4 + rbase;
        const int gg  = gw + mrow;
        {
            const size_t i0 = (size_t)blo * F_DIM + gg;
            out[i0]          = z0;
            out[BF + i0]     = v0;
            out[2 * BF + i0] = c0;
            const size_t i1 = (size_t)(blo + 1) * F_DIM + gg;
            out[i1]          = z1;
            out[BF + i1]     = v1;
            out[2 * BF + i1] = c1;
        }
    }
}

// ---------------- fallback: R3 fp32-input kernel (verified) ----------------
__global__ __launch_bounds__(256, 1)
void lif_kernel_f32(const float* __restrict__ spikes,
                    const float* __restrict__ W,
                    float* __restrict__ out)
{
    __shared__ unsigned short sAf[16 * ROWP];
    __shared__ float xbuf[2 * 256];

    const int tid  = threadIdx.x;
    const int lane = tid & 63;
    const int w    = tid >> 6;
    const int gh   = w & 1;
    const int kh   = w >> 1;
    const int bt   = blockIdx.x & 15;
    const int gb   = blockIdx.x >> 4;
    const int b0   = bt * 16;
    const int gw   = gb * 32 + gh * 16;
    const int mrow = lane & 15;
    const int kq   = lane >> 4;

    short8 whi[8], wmd[8], wlo[8];
    {
        const float* wp = W + (size_t)(gw + mrow) * F_DIM + kh * 256 + kq * 8;
        #pragma unroll
        for (int ks = 0; ks < 8; ++ks) {
            short8 hi, md, lo;
            #pragma unroll
            for (int j = 0; j < 8; ++j) {
                float f = wp[ks * 32 + j];
                unsigned short h = f2bf_rne(f);
                float r1 = f - bf2f(h);
                unsigned short m = f2bf_rne(r1);
                float r2 = r1 - bf2f(m);
                hi[j] = (short)h;
                md[j] = (short)m;
                lo[j] = (short)f2bf_rne(r2);
            }
            whi[ks] = hi; wmd[ks] = md; wlo[ks] = lo;
        }
    }

    float v[4]  = {0.f, 0.f, 0.f, 0.f};
    float cu[4] = {0.f, 0.f, 0.f, 0.f};
    float zf[4] = {0.f, 0.f, 0.f, 0.f};

    floatx4 ld[8];
    auto issue_loads = [&](int t) {
        const floatx4* sp = (const floatx4*)(spikes + (size_t)t * BF + (size_t)b0 * F_DIM);
        #pragma unroll
        for (int j = 0; j < 8; ++j)
            ld[j] = sp[tid + 256 * j];
    };

    issue_loads(0);
    for (int t = 0; t < T_STEPS; ++t) {
        #pragma unroll
        for (int j = 0; j < 8; ++j) {
            const int q = tid + 256 * j;
            const int row = q >> 7, col4 = q & 127;
            unsigned u0 = __float_as_uint(ld[j][0]);
            unsigned u1 = __float_as_uint(ld[j][1]);
            unsigned u2 = __float_as_uint(ld[j][2]);
            unsigned u3 = __float_as_uint(ld[j][3]);
            uintx2 d;
            d[0] = (u0 >> 16) | (u1 & 0xFFFF0000u);
            d[1] = (u2 >> 16) | (u3 & 0xFFFF0000u);
            *(uintx2*)&sAf[row * ROWP + col4 * 4] = d;
        }
        __syncthreads();
        if (t + 1 < T_STEPS) issue_loads(t + 1);

        floatx4 ah = {0.f, 0.f, 0.f, 0.f};
        floatx4 am = {0.f, 0.f, 0.f, 0.f};
        floatx4 al = {0.f, 0.f, 0.f, 0.f};
        const unsigned short* arow = &sAf[mrow * ROWP + kh * 256 + kq * 8];
        #pragma unroll
        for (int ks = 0; ks < 8; ++ks) {
            short8 a = *(const short8*)(arow + ks * 32);
            ah = __builtin_amdgcn_mfma_f32_16x16x32_bf16(a, whi[ks], ah, 0, 0, 0);
            am = __builtin_amdgcn_mfma_f32_16x16x32_bf16(a, wmd[ks], am, 0, 0, 0);
            al = __builtin_amdgcn_mfma_f32_16x16x32_bf16(a, wlo[ks], al, 0, 0, 0);
        }

        if (kh == 1) {
            floatx4 xp = (ah + am) + al;
            *(floatx4*)&xbuf[gh * 256 + lane * 4] = xp;
        }
        __syncthreads();
        if (kh == 0) {
            floatx4 other = *(const floatx4*)&xbuf[gh * 256 + lane * 4];
            #pragma unroll
            for (int r = 0; r < 4; ++r) {
                float x    = ((ah[r] + am[r]) + al[r]) + other[r];
                float vdec = v[r] + 0.1f * ((0.0f - v[r]) + cu[r]);
                float idec = cu[r] - 0.2f * cu[r];
                bool  spk  = (vdec - 1.0f) > 0.0f;
                zf[r] = spk ? 1.0f : 0.0f;
                v[r]  = spk ? 0.0f : vdec;
                cu[r] = idec + x;
            }
        }
    }

    if (kh == 0) {
        #pragma unroll
        for (int r = 0; r < 4; ++r) {
            const size_t idx = (size_t)(b0 + kq * 4 + r) * F_DIM + gw + mrow;
            out[idx]          = zf[r];
            out[BF + idx]     = v[r];
            out[2 * BF + idx] = cu[r];
        }
    }
}

extern "C" void kernel_launch(void* const* d_in, const int* in_sizes, int n_in,
                              void* d_out, int out_size, void* d_ws, size_t ws_size,
                              hipStream_t stream)
{
    const float* spikes = (const float*)d_in[0];   // [T,B,F] fp32
    const float* W      = (const float*)d_in[1];   // [F,F]   fp32
    float* out          = (float*)d_out;           // [3,B,F] fp32

    const size_t need_bits = (size_t)T_STEPS * B_DIM * (F_DIM / 8);   // 16 MiB

    if (d_ws != nullptr && ws_size >= need_bits) {
        unsigned* bits = (unsigned*)d_ws;
        pack_kernel<<<dim3(2048), dim3(256), 0, stream>>>(spikes, bits);
        lif_kernel_bits<<<dim3(512), dim3(512), 0, stream>>>(bits, W, out);
    } else {
        lif_kernel_f32<<<dim3(256), dim3(256), 0, stream>>>(spikes, W, out);
    }
}